// Round 8
// baseline (153.981 us; speedup 1.0000x reference)
//
#include <hip/hip_runtime.h>
#include <math.h>

#define BB 64
#define LL 512
#define DD 512
#define CC 50
#define NC 100
#define NCP 112

// ws byte layout:
//   0: loss f32   4: cnt f32   8: done counter (int)
//   64:      scomb f32 [64][112]                   (28672 B)
//   28736:   span partials bf16 [8 seg][64 b][512] (524288 B)
//   553024:  Wbot bf16 [112][512] (rows 100..111 = poison, masked downstream)
//   667712:  Bpack bf16 fragment-packed [112 frag][64 ln][8] (114688 B)
#define WSB_LOSS  0
#define WSB_CNT   4
#define WSB_DONE  8
#define WSB_SCOMB 64
#define WSB_PART  28736
#define WSB_WBOT  553024
#define WSB_BPACK 667712

typedef __attribute__((ext_vector_type(8))) short bf16x8;
typedef __attribute__((ext_vector_type(4))) float f32x4;

static __device__ __forceinline__ unsigned short f2bf(float x) {
    unsigned int u = __float_as_uint(x);
    u += 0x7FFFu + ((u >> 16) & 1u);          // RNE
    return (unsigned short)(u >> 16);
}
static __device__ __forceinline__ float bf2f(unsigned short h) {
    return __uint_as_float(((unsigned int)h) << 16);
}
// pack two f32 -> bf16x2 (truncation): low short = hi16(a), high = hi16(b)
static __device__ __forceinline__ unsigned int pk2bf(float a, float b) {
    return __builtin_amdgcn_perm(__float_as_uint(b), __float_as_uint(a), 0x07060302u);
}
static __device__ __forceinline__ void gl2lds16(const void* g, void* l) {
    __builtin_amdgcn_global_load_lds(
        (const __attribute__((address_space(1))) unsigned int*)g,
        (__attribute__((address_space(3))) unsigned int*)l, 16, 0, 0);
}

// ---------------------------------------------------------------------------
// k_prep, grid 536:
//  blocks [0,512): span partials. block=(b<<3)|seg, rows [seg*64,+64)∩[start,end]
//    -> bf16 partial[seg][b][512] (zeros if empty).
//  blocks [512,520): W bottom-half transpose -> Wbot bf16 [mat*50+n][512].
//    block 512 zeroes loss/cnt/done.
//  blocks [520,536): Bpack: W top-half -> MFMA-fragment-packed bf16.
//    frag fid = s*7+u; element [ln*8+j] = W[s*32+quad*8+j][u*16+tc], tc=ln&15.
// ---------------------------------------------------------------------------
__global__ __launch_bounds__(256) void k_prep(
    const float* __restrict__ tv, const int* __restrict__ sbj_bound,
    const float* __restrict__ Wst, const float* __restrict__ Wen,
    char* __restrict__ wsb)
{
    __shared__ float sh[128 * 53];
    const int t = threadIdx.x;
    const int blk = blockIdx.x;

    if (blk < 512) {
        const int b = blk >> 3, seg = blk & 7;
        const int start = sbj_bound[2 * b], end = sbj_bound[2 * b + 1];
        int r0 = seg * 64;      if (r0 < start) r0 = start;
        int r1 = seg * 64 + 63; if (r1 > end)   r1 = end;
        const int c4 = t & 127, par = t >> 7;
        const float* bp = tv + (size_t)b * LL * DD + c4 * 4;
        float4 a0 = {0, 0, 0, 0}, a1 = {0, 0, 0, 0};
        int r = r0 + par;
        for (; r + 2 <= r1; r += 4) {
            float4 v0 = *(const float4*)(bp + (size_t)r * DD);
            float4 v1 = *(const float4*)(bp + (size_t)(r + 2) * DD);
            a0.x += v0.x; a0.y += v0.y; a0.z += v0.z; a0.w += v0.w;
            a1.x += v1.x; a1.y += v1.y; a1.z += v1.z; a1.w += v1.w;
        }
        for (; r <= r1; r += 2) {
            float4 v0 = *(const float4*)(bp + (size_t)r * DD);
            a0.x += v0.x; a0.y += v0.y; a0.z += v0.z; a0.w += v0.w;
        }
        float4* buf = (float4*)sh;
        float4 acc = {a0.x + a1.x, a0.y + a1.y, a0.z + a1.z, a0.w + a1.w};
        buf[t] = acc;
        __syncthreads();
        if (t < 128) {
            float4 x = buf[t], y = buf[t + 128];
            unsigned short* part = (unsigned short*)(wsb + WSB_PART);
            ushort4 o;
            o.x = f2bf(x.x + y.x); o.y = f2bf(x.y + y.y);
            o.z = f2bf(x.z + y.z); o.w = f2bf(x.w + y.w);
            *(ushort4*)(part + ((size_t)(seg * BB + b)) * DD + t * 4) = o;
        }
    } else if (blk < 520) {
        const int bi = blk - 512;              // 0..7
        const int mat = bi >> 2;               // 0: W_start, 1: W_end
        const int cj = bi & 3;                 // 128-row chunk of k in [512,1024)
        const float* W = mat ? Wen : Wst;
        const int kbase = 512 + cj * 128;
        const float* src = W + (size_t)kbase * CC;
#pragma unroll
        for (int i = 0; i < 25; i++) {
            int idx = t + i * 256;             // [0,6400)
            sh[idx] = src[idx];                // sh[kr*50+c] laid as kr*53? no:
        }
        __syncthreads();
        // re-read with transpose-friendly indexing (sh holds linear kr*50+c)
        unsigned short* outp = (unsigned short*)(wsb + WSB_WBOT);
        const int kout = cj * 128;
#pragma unroll
        for (int i = 0; i < 25; i++) {
            int idx = t + i * 256;             // 50 n x 128 kl
            int n = idx >> 7, kl = idx & 127;
            outp[((size_t)(mat * CC + n)) * DD + kout + kl] = f2bf(sh[kl * 50 + n]);
        }
        if (bi == 0 && t == 0) {
            *(float*)(wsb + WSB_LOSS) = 0.0f;
            *(float*)(wsb + WSB_CNT)  = 0.0f;
            *(int*)(wsb + WSB_DONE)   = 0;
        }
    } else {
        const int bi = blk - 520;              // 0..15
        const int ln = t & 63, jj = t >> 6;    // jj 0..3
        const int tc = ln & 15, quad = ln >> 4;
        const int j0 = jj * 2;
        unsigned int* bp = (unsigned int*)(wsb + WSB_BPACK);
#pragma unroll
        for (int q = 0; q < 7; q++) {
            const int fid = bi * 7 + q;        // 0..111
            const int u = fid % 7, s = fid / 7;
            const int cc = u * 16 + tc;
            const int k0 = s * 32 + quad * 8 + j0;
            float a = 0.f, bb = 0.f;
            if (cc < CC) {
                a  = Wst[(size_t)k0 * CC + cc];
                bb = Wst[(size_t)(k0 + 1) * CC + cc];
            } else if (cc < NC) {
                a  = Wen[(size_t)k0 * CC + cc - CC];
                bb = Wen[(size_t)(k0 + 1) * CC + cc - CC];
            }
            bp[fid * 256 + ln * 4 + jj] =
                (unsigned int)f2bf(a) | ((unsigned int)f2bf(bb) << 16);
        }
    }
}

// ---------------------------------------------------------------------------
// k_scomb: 4 blocks x 16 batches. Combine 8 seg-partials -> sbj bf16 LDS
// (div by span count), then per-wave column strips of sbj @ Wbot^T -> scomb.
// ---------------------------------------------------------------------------
#define SST 520
__global__ __launch_bounds__(256) void k_scomb(
    const int* __restrict__ sbj_bound,
    const float* __restrict__ bst, const float* __restrict__ ben,
    char* __restrict__ wsb)
{
    __shared__ __align__(16) unsigned short sbjb[16 * SST];
    const int t = threadIdx.x;
    const int g = blockIdx.x;
    const unsigned short* part = (const unsigned short*)(wsb + WSB_PART);

#pragma unroll
    for (int i = 0; i < 8; i++) {
        int idx = t + i * 256;                 // [0, 2048)
        int bo = idx >> 7, d4 = idx & 127;
        int b = g * 16 + bo;
        float inv = 1.0f / (float)(sbj_bound[2 * b + 1] - sbj_bound[2 * b] + 1);
        float sx = 0.f, sy = 0.f, sz = 0.f, sw = 0.f;
#pragma unroll
        for (int seg = 0; seg < 8; seg++) {
            ushort4 v = *(const ushort4*)(part + ((size_t)(seg * BB + b)) * DD + d4 * 4);
            sx += bf2f(v.x); sy += bf2f(v.y); sz += bf2f(v.z); sw += bf2f(v.w);
        }
        ushort4 o;
        o.x = f2bf(sx * inv); o.y = f2bf(sy * inv);
        o.z = f2bf(sz * inv); o.w = f2bf(sw * inv);
        *(ushort4*)(sbjb + bo * SST + d4 * 4) = o;
    }
    __syncthreads();

    const int wv = t >> 6, ln = t & 63, tc = ln & 15, quad = ln >> 4;
    const unsigned short* wbot = (const unsigned short*)(wsb + WSB_WBOT);
    float* scomb = (float*)(wsb + WSB_SCOMB);
    const unsigned short* Af = sbjb + tc * SST + quad * 8;
    const int nu = (wv < 3) ? 2 : 1;
    for (int j = 0; j < nu; j++) {
        const int u = wv * 2 + j;
        f32x4 acc = (f32x4)(0.0f);
        const unsigned short* Bf = wbot + (size_t)(u * 16 + tc) * DD + quad * 8;
#pragma unroll
        for (int kk = 0; kk < DD; kk += 32) {
            bf16x8 af = *(const bf16x8*)(Af + kk);
            bf16x8 bf = *(const bf16x8*)(Bf + kk);
            acc = __builtin_amdgcn_mfma_f32_16x16x32_bf16(af, bf, acc, 0, 0, 0);
        }
        const int cc = u * 16 + tc;
        const float bias = (cc < CC) ? bst[cc] : ((cc < NC) ? ben[cc - CC] : 0.0f);
#pragma unroll
        for (int i = 0; i < 4; i++) {
            int b = g * 16 + quad * 4 + i;
            scomb[b * NCP + cc] = acc[i] + bias;
        }
    }
}

// ---------------------------------------------------------------------------
// k_main: 512 blocks x 256 thr (4 waves, 64 rows/block, 2 generations).
// Bpack staged to LDS via gl2lds (linear, conflict-free frag reads at ln*16).
// A streamed f32 global->VGPR in double-buffered 8x-float4 batches (32 VGPRs,
// distance-1 prefetch, no K-loop barriers). v_perm pack -> MFMA. Fused CE.
// ---------------------------------------------------------------------------
__global__ __launch_bounds__(256, 1) void k_main(
    const float* __restrict__ tv,
    const int* __restrict__ mask,
    const int* __restrict__ obj_s, const int* __restrict__ obj_e,
    char* __restrict__ wsb, float* __restrict__ out)
{
    __shared__ __align__(16) unsigned short Bl[112 * 512];   // 114688 B
    __shared__ float red[8];
    const int t = threadIdx.x, wv = t >> 6, ln = t & 63;
    const int tc = ln & 15, quad = ln >> 4;
    const int m0 = blockIdx.x * 64;
    const int b = blockIdx.x >> 3;

    const float* Ap = tv + (size_t)(m0 + wv * 16 + tc) * DD + quad * 8;

    // A batches 0,1 issued first (in flight across B staging + barrier)
    float4 ra0[8], ra1[8];
#pragma unroll
    for (int ks = 0; ks < 4; ks++) {
        ra0[2 * ks]     = *(const float4*)(Ap + ks * 32);
        ra0[2 * ks + 1] = *(const float4*)(Ap + ks * 32 + 4);
    }
#pragma unroll
    for (int ks = 0; ks < 4; ks++) {
        ra1[2 * ks]     = *(const float4*)(Ap + (4 + ks) * 32);
        ra1[2 * ks + 1] = *(const float4*)(Ap + (4 + ks) * 32 + 4);
    }
    // stage Bpack -> LDS, zero VGPR traffic (7168 granules of 16B)
    {
        const char* gB = wsb + WSB_BPACK;
#pragma unroll
        for (int i = 0; i < 28; i++) {
            const int gidx = t + i * 256;
            gl2lds16(gB + (size_t)gidx * 16,
                     (char*)Bl + (i * 256 + wv * 64) * 16);
        }
    }
    __syncthreads();

    f32x4 acc[7];
#pragma unroll
    for (int u = 0; u < 7; u++) acc[u] = (f32x4)(0.0f);
    const unsigned short* Bf0 = Bl + ln * 8;

#pragma unroll
    for (int bt = 0; bt < 4; bt++) {
        float4* cur = (bt & 1) ? ra1 : ra0;
#pragma unroll
        for (int ks = 0; ks < 4; ks++) {
            const int s = bt * 4 + ks;
            float4 v0 = cur[2 * ks], v1 = cur[2 * ks + 1];
            union { unsigned int u32[4]; bf16x8 v; } af;
            af.u32[0] = pk2bf(v0.x, v0.y);
            af.u32[1] = pk2bf(v0.z, v0.w);
            af.u32[2] = pk2bf(v1.x, v1.y);
            af.u32[3] = pk2bf(v1.z, v1.w);
#pragma unroll
            for (int u = 0; u < 7; u++) {
                bf16x8 bf = *(const bf16x8*)(Bf0 + (s * 7 + u) * 512);
                acc[u] = __builtin_amdgcn_mfma_f32_16x16x32_bf16(af.v, bf, acc[u], 0, 0, 0);
            }
        }
        if (bt < 2) {   // prefetch batch bt+2 into the buffer just consumed
#pragma unroll
            for (int ks = 0; ks < 4; ks++) {
                cur[2 * ks]     = *(const float4*)(Ap + (4 * (bt + 2) + ks) * 32);
                cur[2 * ks + 1] = *(const float4*)(Ap + (4 * (bt + 2) + ks) * 32 + 4);
            }
        }
    }

    // ---- fused CE epilogue (C/D: col=lane&15, row=quad*4+reg) ----
    const float* scomb = (const float*)(wsb + WSB_SCOMB);
    float sc[7];
#pragma unroll
    for (int u = 0; u < 7; u++) sc[u] = scomb[b * NCP + u * 16 + tc];

    float loss_local = 0.0f, cnt_local = 0.0f;
#pragma unroll
    for (int i = 0; i < 4; i++) {
        const int l = (m0 + wv * 16 + quad * 4 + i) & (LL - 1);
        const int lab1 = obj_s[b * LL + l];
        const int lab2 = obj_e[b * LL + l] + CC;
        const int mk   = mask[b * LL + l];
        float lg[7];
#pragma unroll
        for (int u = 0; u < 7; u++) lg[u] = acc[u][i] + sc[u];
        float m1 = fmaxf(fmaxf(lg[0], lg[1]), lg[2]);
        if (tc < 2) m1 = fmaxf(m1, lg[3]);
        float m2 = fmaxf(lg[4], lg[5]);
        if (tc >= 2) m2 = fmaxf(m2, lg[3]);
        if (tc < 4)  m2 = fmaxf(m2, lg[6]);
#pragma unroll
        for (int off = 1; off < 16; off <<= 1) {
            m1 = fmaxf(m1, __shfl_xor(m1, off, 16));
            m2 = fmaxf(m2, __shfl_xor(m2, off, 16));
        }
        float e1 = expf(lg[0] - m1) + expf(lg[1] - m1) + expf(lg[2] - m1)
                 + ((tc < 2) ? expf(lg[3] - m1) : 0.0f);
        float e2 = expf(lg[4] - m2) + expf(lg[5] - m2)
                 + ((tc >= 2) ? expf(lg[3] - m2) : 0.0f)
                 + ((tc < 4)  ? expf(lg[6] - m2) : 0.0f);
        float t1 = 0.0f, t2 = 0.0f;
#pragma unroll
        for (int u = 0; u < 7; u++) {
            const int cc = u * 16 + tc;
            if (cc == lab1) t1 = lg[u];
            if (cc == lab2) t2 = lg[u];
        }
#pragma unroll
        for (int off = 1; off < 16; off <<= 1) {
            e1 += __shfl_xor(e1, off, 16);
            e2 += __shfl_xor(e2, off, 16);
            t1 += __shfl_xor(t1, off, 16);
            t2 += __shfl_xor(t2, off, 16);
        }
        if (tc == 0) {
            const float nll = (m1 + logf(e1) - t1) + (m2 + logf(e2) - t2);
            loss_local += mk ? nll : 0.0f;
            cnt_local  += mk ? 1.0f : 0.0f;
        }
    }
#pragma unroll
    for (int off = 1; off < 64; off <<= 1) {
        loss_local += __shfl_xor(loss_local, off);
        cnt_local  += __shfl_xor(cnt_local, off);
    }
    if (ln == 0) { red[wv * 2] = loss_local; red[wv * 2 + 1] = cnt_local; }
    __syncthreads();
    if (t == 0) {
        float Ls = red[0] + red[2] + red[4] + red[6];
        float Cs = red[1] + red[3] + red[5] + red[7];
        float* wsf = (float*)wsb;
        atomicAdd(&wsf[0], Ls);
        atomicAdd(&wsf[1], Cs);
        __threadfence();
        int old = atomicAdd((int*)(wsb + WSB_DONE), 1);
        if (old == (int)gridDim.x - 1) {
            float L = atomicAdd(&wsf[0], 0.0f);   // coherent read
            float C = atomicAdd(&wsf[1], 0.0f);
            out[0] = L / C;
        }
    }
}

extern "C" void kernel_launch(void* const* d_in, const int* in_sizes, int n_in,
                              void* d_out, int out_size, void* d_ws, size_t ws_size,
                              hipStream_t stream) {
    const float* tv   = (const float*)d_in[0];
    const int*   mask = (const int*)d_in[1];
    const int*   sbj  = (const int*)d_in[2];
    const int*   objs = (const int*)d_in[3];
    const int*   obje = (const int*)d_in[4];
    const float* Wst  = (const float*)d_in[5];
    const float* bst  = (const float*)d_in[6];
    const float* Wen  = (const float*)d_in[7];
    const float* ben  = (const float*)d_in[8];
    float* out = (float*)d_out;
    char*  wsb = (char*)d_ws;

    k_prep<<<536, 256, 0, stream>>>(tv, sbj, Wst, Wen, wsb);
    k_scomb<<<4, 256, 0, stream>>>(sbj, bst, ben, wsb);
    k_main<<<512, 256, 0, stream>>>(tv, mask, objs, obje, wsb, out);
}

// Round 9
// 145.213 us; speedup vs baseline: 1.0604x; 1.0604x over previous
//
#include <hip/hip_runtime.h>
#include <math.h>

#define BB 64
#define LL 512
#define DD 512
#define CC 50
#define NC 100
#define NCP 112

// ws byte layout:
//   0: loss f32   4: cnt f32   8: done counter (int)
//   64:      scomb f32 [64][112]                   (28672 B)
//   28736:   span partials bf16 [8 seg][64 b][512] (524288 B)
//   553024:  Wbot bf16 [112][512] (rows 100..111 unused)
//   667712:  Bpack bf16 fragment-packed [112 frag][64 ln][8] (114688 B)
#define WSB_LOSS  0
#define WSB_CNT   4
#define WSB_DONE  8
#define WSB_SCOMB 64
#define WSB_PART  28736
#define WSB_WBOT  553024
#define WSB_BPACK 667712

typedef __attribute__((ext_vector_type(8))) short bf16x8;
typedef __attribute__((ext_vector_type(4))) float f32x4;

static __device__ __forceinline__ unsigned short f2bf(float x) {
    unsigned int u = __float_as_uint(x);
    u += 0x7FFFu + ((u >> 16) & 1u);          // RNE
    return (unsigned short)(u >> 16);
}
static __device__ __forceinline__ float bf2f(unsigned short h) {
    return __uint_as_float(((unsigned int)h) << 16);
}
// pack two f32 -> bf16x2 (truncate): low short = hi16(a), high = hi16(b)
static __device__ __forceinline__ unsigned int pk2bf(float a, float b) {
    return __builtin_amdgcn_perm(__float_as_uint(b), __float_as_uint(a), 0x07060302u);
}
static __device__ __forceinline__ void gl2lds16(const void* g, void* l) {
    __builtin_amdgcn_global_load_lds(
        (const __attribute__((address_space(1))) unsigned int*)g,
        (__attribute__((address_space(3))) unsigned int*)l, 16, 0, 0);
}

// ---------------------------------------------------------------------------
// k_prep (unchanged from R8): span partials / Wbot transpose / Bpack build.
// ---------------------------------------------------------------------------
__global__ __launch_bounds__(256) void k_prep(
    const float* __restrict__ tv, const int* __restrict__ sbj_bound,
    const float* __restrict__ Wst, const float* __restrict__ Wen,
    char* __restrict__ wsb)
{
    __shared__ float sh[128 * 53];
    const int t = threadIdx.x;
    const int blk = blockIdx.x;

    if (blk < 512) {
        const int b = blk >> 3, seg = blk & 7;
        const int start = sbj_bound[2 * b], end = sbj_bound[2 * b + 1];
        int r0 = seg * 64;      if (r0 < start) r0 = start;
        int r1 = seg * 64 + 63; if (r1 > end)   r1 = end;
        const int c4 = t & 127, par = t >> 7;
        const float* bp = tv + (size_t)b * LL * DD + c4 * 4;
        float4 a0 = {0, 0, 0, 0}, a1 = {0, 0, 0, 0};
        int r = r0 + par;
        for (; r + 2 <= r1; r += 4) {
            float4 v0 = *(const float4*)(bp + (size_t)r * DD);
            float4 v1 = *(const float4*)(bp + (size_t)(r + 2) * DD);
            a0.x += v0.x; a0.y += v0.y; a0.z += v0.z; a0.w += v0.w;
            a1.x += v1.x; a1.y += v1.y; a1.z += v1.z; a1.w += v1.w;
        }
        for (; r <= r1; r += 2) {
            float4 v0 = *(const float4*)(bp + (size_t)r * DD);
            a0.x += v0.x; a0.y += v0.y; a0.z += v0.z; a0.w += v0.w;
        }
        float4* buf = (float4*)sh;
        float4 acc = {a0.x + a1.x, a0.y + a1.y, a0.z + a1.z, a0.w + a1.w};
        buf[t] = acc;
        __syncthreads();
        if (t < 128) {
            float4 x = buf[t], y = buf[t + 128];
            unsigned short* part = (unsigned short*)(wsb + WSB_PART);
            ushort4 o;
            o.x = f2bf(x.x + y.x); o.y = f2bf(x.y + y.y);
            o.z = f2bf(x.z + y.z); o.w = f2bf(x.w + y.w);
            *(ushort4*)(part + ((size_t)(seg * BB + b)) * DD + t * 4) = o;
        }
    } else if (blk < 520) {
        const int bi = blk - 512;              // 0..7
        const int mat = bi >> 2;               // 0: W_start, 1: W_end
        const int cj = bi & 3;                 // 128-row chunk of k in [512,1024)
        const float* W = mat ? Wen : Wst;
        const int kbase = 512 + cj * 128;
        const float* src = W + (size_t)kbase * CC;
#pragma unroll
        for (int i = 0; i < 25; i++) {
            int idx = t + i * 256;             // [0,6400)
            sh[idx] = src[idx];
        }
        __syncthreads();
        unsigned short* outp = (unsigned short*)(wsb + WSB_WBOT);
        const int kout = cj * 128;
#pragma unroll
        for (int i = 0; i < 25; i++) {
            int idx = t + i * 256;             // 50 n x 128 kl
            int n = idx >> 7, kl = idx & 127;
            outp[((size_t)(mat * CC + n)) * DD + kout + kl] = f2bf(sh[kl * 50 + n]);
        }
        if (bi == 0 && t == 0) {
            *(float*)(wsb + WSB_LOSS) = 0.0f;
            *(float*)(wsb + WSB_CNT)  = 0.0f;
            *(int*)(wsb + WSB_DONE)   = 0;
        }
    } else {
        const int bi = blk - 520;              // 0..15
        const int ln = t & 63, jj = t >> 6;    // jj 0..3
        const int tc = ln & 15, quad = ln >> 4;
        const int j0 = jj * 2;
        unsigned int* bp = (unsigned int*)(wsb + WSB_BPACK);
#pragma unroll
        for (int q = 0; q < 7; q++) {
            const int fid = bi * 7 + q;        // 0..111
            const int u = fid % 7, s = fid / 7;
            const int cc = u * 16 + tc;
            const int k0 = s * 32 + quad * 8 + j0;
            float a = 0.f, bb = 0.f;
            if (cc < CC) {
                a  = Wst[(size_t)k0 * CC + cc];
                bb = Wst[(size_t)(k0 + 1) * CC + cc];
            } else if (cc < NC) {
                a  = Wen[(size_t)k0 * CC + cc - CC];
                bb = Wen[(size_t)(k0 + 1) * CC + cc - CC];
            }
            bp[fid * 256 + ln * 4 + jj] =
                (unsigned int)f2bf(a) | ((unsigned int)f2bf(bb) << 16);
        }
    }
}

// ---------------------------------------------------------------------------
// k_scomb (unchanged): combine seg-partials -> sbj, sbj @ Wbot^T -> scomb.
// ---------------------------------------------------------------------------
#define SST 520
__global__ __launch_bounds__(256) void k_scomb(
    const int* __restrict__ sbj_bound,
    const float* __restrict__ bst, const float* __restrict__ ben,
    char* __restrict__ wsb)
{
    __shared__ __align__(16) unsigned short sbjb[16 * SST];
    const int t = threadIdx.x;
    const int g = blockIdx.x;
    const unsigned short* part = (const unsigned short*)(wsb + WSB_PART);

#pragma unroll
    for (int i = 0; i < 8; i++) {
        int idx = t + i * 256;                 // [0, 2048)
        int bo = idx >> 7, d4 = idx & 127;
        int b = g * 16 + bo;
        float inv = 1.0f / (float)(sbj_bound[2 * b + 1] - sbj_bound[2 * b] + 1);
        float sx = 0.f, sy = 0.f, sz = 0.f, sw = 0.f;
#pragma unroll
        for (int seg = 0; seg < 8; seg++) {
            ushort4 v = *(const ushort4*)(part + ((size_t)(seg * BB + b)) * DD + d4 * 4);
            sx += bf2f(v.x); sy += bf2f(v.y); sz += bf2f(v.z); sw += bf2f(v.w);
        }
        ushort4 o;
        o.x = f2bf(sx * inv); o.y = f2bf(sy * inv);
        o.z = f2bf(sz * inv); o.w = f2bf(sw * inv);
        *(ushort4*)(sbjb + bo * SST + d4 * 4) = o;
    }
    __syncthreads();

    const int wv = t >> 6, ln = t & 63, tc = ln & 15, quad = ln >> 4;
    const unsigned short* wbot = (const unsigned short*)(wsb + WSB_WBOT);
    float* scomb = (float*)(wsb + WSB_SCOMB);
    const unsigned short* Af = sbjb + tc * SST + quad * 8;
    const int nu = (wv < 3) ? 2 : 1;
    for (int j = 0; j < nu; j++) {
        const int u = wv * 2 + j;
        f32x4 acc = (f32x4)(0.0f);
        const unsigned short* Bf = wbot + (size_t)(u * 16 + tc) * DD + quad * 8;
#pragma unroll
        for (int kk = 0; kk < DD; kk += 32) {
            bf16x8 af = *(const bf16x8*)(Af + kk);
            bf16x8 bf = *(const bf16x8*)(Bf + kk);
            acc = __builtin_amdgcn_mfma_f32_16x16x32_bf16(af, bf, acc, 0, 0, 0);
        }
        const int cc = u * 16 + tc;
        const float bias = (cc < CC) ? bst[cc] : ((cc < NC) ? ben[cc - CC] : 0.0f);
#pragma unroll
        for (int i = 0; i < 4; i++) {
            int b = g * 16 + quad * 4 + i;
            scomb[b * NCP + cc] = acc[i] + bias;
        }
    }
}

// ---------------------------------------------------------------------------
// k_main: 256 blocks x 256 thr, 1 block/CU, ONE generation (128 rows/block).
// B frag-packed staged ONCE to LDS via gl2lds. Each wave owns 32 rows and a
// private 2x4KB LDS A double-buffer fed by gl2lds (XOR-swizzled granules);
// NO barriers in the K-loop — waves run free, vmcnt stalls overlap across
// waves. 2 M-tiles x 7 col-frags per wave. Fused CE epilogue.
// ---------------------------------------------------------------------------
__global__ __launch_bounds__(256, 1) void k_main(
    const float* __restrict__ tv,
    const int* __restrict__ mask,
    const int* __restrict__ obj_s, const int* __restrict__ obj_e,
    char* __restrict__ wsb, float* __restrict__ out)
{
    __shared__ __align__(16) unsigned short Bl[112 * 512];   // 114688 B
    __shared__ __align__(16) float Aw[4 * 2 * 1024];         // 32768 B
    __shared__ float red[8];
    const int t = threadIdx.x, wv = t >> 6, ln = t & 63;
    const int tc = ln & 15, quad = ln >> 4;
    const int m0 = blockIdx.x * 128;
    const int wr0 = m0 + wv * 32;          // this wave's 32 rows
    const int b = blockIdx.x >> 2;

    // per-lane A source: granule (row rl, swizzled col) of a 32-row k-chunk
    const int rl = ln >> 3;                // 0..7
    const int gsw = (ln & 7) ^ rl;         // stored col granule = (ln&7)^rl
    const float* asrc = tv + (size_t)(wr0 + rl) * DD + gsw * 4;
    float* Asl0 = Aw + wv * 2048;
    float* Asl1 = Aw + wv * 2048 + 1024;

    // ---- stage B (shared) first, then A chunks 0,1 ----
    {
        const char* gB = wsb + WSB_BPACK;
#pragma unroll
        for (int i = 0; i < 28; i++) {
            const int gidx = t + i * 256;
            gl2lds16(gB + (size_t)gidx * 16, (char*)Bl + (i * 256 + wv * 64) * 16);
        }
    }
#pragma unroll
    for (int j = 0; j < 4; j++)
        gl2lds16(asrc + (size_t)j * 8 * DD, (char*)(Asl0 + j * 256));
#pragma unroll
    for (int j = 0; j < 4; j++)
        gl2lds16(asrc + (size_t)j * 8 * DD + 32, (char*)(Asl1 + j * 256));
    __syncthreads();   // B visible to all waves; drains A c0/c1 too

    f32x4 acc0[7], acc1[7];
#pragma unroll
    for (int u = 0; u < 7; u++) { acc0[u] = (f32x4)(0.0f); acc1[u] = (f32x4)(0.0f); }
    const unsigned short* Bf0 = Bl + ln * 8;
    const int R0 = tc, R1 = 16 + tc;
    const int x0 = (quad * 2) ^ (tc & 7), x1 = (quad * 2 + 1) ^ (tc & 7);

#pragma unroll
    for (int s = 0; s < 16; s++) {
        float* Asl = (s & 1) ? Asl1 : Asl0;
        float4 v00 = *(const float4*)(Asl + R0 * 32 + x0 * 4);
        float4 v01 = *(const float4*)(Asl + R0 * 32 + x1 * 4);
        float4 v10 = *(const float4*)(Asl + R1 * 32 + x0 * 4);
        float4 v11 = *(const float4*)(Asl + R1 * 32 + x1 * 4);
        // prefetch chunk s+2 into this slot (reads of the slot are done)
        if (s < 14) {
#pragma unroll
            for (int j = 0; j < 4; j++)
                gl2lds16(asrc + (size_t)j * 8 * DD + (s + 2) * 32,
                         (char*)(Asl + j * 256));
        }
        union { unsigned int u32[4]; bf16x8 v; } af0, af1;
        af0.u32[0] = pk2bf(v00.x, v00.y); af0.u32[1] = pk2bf(v00.z, v00.w);
        af0.u32[2] = pk2bf(v01.x, v01.y); af0.u32[3] = pk2bf(v01.z, v01.w);
        af1.u32[0] = pk2bf(v10.x, v10.y); af1.u32[1] = pk2bf(v10.z, v10.w);
        af1.u32[2] = pk2bf(v11.x, v11.y); af1.u32[3] = pk2bf(v11.z, v11.w);
#pragma unroll
        for (int u = 0; u < 7; u++) {
            bf16x8 bf = *(const bf16x8*)(Bf0 + (s * 7 + u) * 512);
            acc0[u] = __builtin_amdgcn_mfma_f32_16x16x32_bf16(af0.v, bf, acc0[u], 0, 0, 0);
            acc1[u] = __builtin_amdgcn_mfma_f32_16x16x32_bf16(af1.v, bf, acc1[u], 0, 0, 0);
        }
    }

    // ---- fused CE epilogue (C/D: col=lane&15, row=quad*4+reg) ----
    const float* scomb = (const float*)(wsb + WSB_SCOMB);
    float sc[7];
#pragma unroll
    for (int u = 0; u < 7; u++) sc[u] = scomb[b * NCP + u * 16 + tc];

    float loss_local = 0.0f, cnt_local = 0.0f;
#pragma unroll
    for (int mt = 0; mt < 2; mt++) {
        f32x4* acc = mt ? acc1 : acc0;
#pragma unroll
        for (int i = 0; i < 4; i++) {
            const int l = (wr0 + mt * 16 + quad * 4 + i) & (LL - 1);
            const int lab1 = obj_s[b * LL + l];
            const int lab2 = obj_e[b * LL + l] + CC;
            const int mk   = mask[b * LL + l];
            float lg[7];
#pragma unroll
            for (int u = 0; u < 7; u++) lg[u] = acc[u][i] + sc[u];
            float m1 = fmaxf(fmaxf(lg[0], lg[1]), lg[2]);
            if (tc < 2) m1 = fmaxf(m1, lg[3]);
            float m2 = fmaxf(lg[4], lg[5]);
            if (tc >= 2) m2 = fmaxf(m2, lg[3]);
            if (tc < 4)  m2 = fmaxf(m2, lg[6]);
#pragma unroll
            for (int off = 1; off < 16; off <<= 1) {
                m1 = fmaxf(m1, __shfl_xor(m1, off, 16));
                m2 = fmaxf(m2, __shfl_xor(m2, off, 16));
            }
            float e1 = expf(lg[0] - m1) + expf(lg[1] - m1) + expf(lg[2] - m1)
                     + ((tc < 2) ? expf(lg[3] - m1) : 0.0f);
            float e2 = expf(lg[4] - m2) + expf(lg[5] - m2)
                     + ((tc >= 2) ? expf(lg[3] - m2) : 0.0f)
                     + ((tc < 4)  ? expf(lg[6] - m2) : 0.0f);
            float t1 = 0.0f, t2 = 0.0f;
#pragma unroll
            for (int u = 0; u < 7; u++) {
                const int cc = u * 16 + tc;
                if (cc == lab1) t1 = lg[u];
                if (cc == lab2) t2 = lg[u];
            }
#pragma unroll
            for (int off = 1; off < 16; off <<= 1) {
                e1 += __shfl_xor(e1, off, 16);
                e2 += __shfl_xor(e2, off, 16);
                t1 += __shfl_xor(t1, off, 16);
                t2 += __shfl_xor(t2, off, 16);
            }
            if (tc == 0) {
                const float nll = (m1 + logf(e1) - t1) + (m2 + logf(e2) - t2);
                loss_local += mk ? nll : 0.0f;
                cnt_local  += mk ? 1.0f : 0.0f;
            }
        }
    }
#pragma unroll
    for (int off = 1; off < 64; off <<= 1) {
        loss_local += __shfl_xor(loss_local, off);
        cnt_local  += __shfl_xor(cnt_local, off);
    }
    if (ln == 0) { red[wv * 2] = loss_local; red[wv * 2 + 1] = cnt_local; }
    __syncthreads();
    if (t == 0) {
        float Ls = red[0] + red[2] + red[4] + red[6];
        float Cs = red[1] + red[3] + red[5] + red[7];
        float* wsf = (float*)wsb;
        atomicAdd(&wsf[0], Ls);
        atomicAdd(&wsf[1], Cs);
        __threadfence();
        int old = atomicAdd((int*)(wsb + WSB_DONE), 1);
        if (old == (int)gridDim.x - 1) {
            float L = atomicAdd(&wsf[0], 0.0f);   // coherent read
            float C = atomicAdd(&wsf[1], 0.0f);
            out[0] = L / C;
        }
    }
}

extern "C" void kernel_launch(void* const* d_in, const int* in_sizes, int n_in,
                              void* d_out, int out_size, void* d_ws, size_t ws_size,
                              hipStream_t stream) {
    const float* tv   = (const float*)d_in[0];
    const int*   mask = (const int*)d_in[1];
    const int*   sbj  = (const int*)d_in[2];
    const int*   objs = (const int*)d_in[3];
    const int*   obje = (const int*)d_in[4];
    const float* Wst  = (const float*)d_in[5];
    const float* bst  = (const float*)d_in[6];
    const float* Wen  = (const float*)d_in[7];
    const float* ben  = (const float*)d_in[8];
    float* out = (float*)d_out;
    char*  wsb = (char*)d_ws;

    k_prep<<<536, 256, 0, stream>>>(tv, sbj, Wst, Wen, wsb);
    k_scomb<<<4, 256, 0, stream>>>(sbj, bst, ben, wsb);
    k_main<<<256, 256, 0, stream>>>(tv, mask, objs, obje, wsb, out);
}